// Round 5
// baseline (261.774 us; speedup 1.0000x reference)
//
#include <hip/hip_runtime.h>

// cost[b,dd,ii,j,c,uv] = (bounds? x[b,c,uv, ii+d*(4-u), j+d*(4-v)] : 0) * mask[b,uv,ii,j]
// d = dd-4, u=uv/9, v=uv%9.  out = cost (b,9,96,96,324) flat, then ctr = x[:,:,40,:,:].
//
// v5 = R3 + software pipeline: one block per (ii,dd,b) sweeps 6 sub-chunks of
// 16 j with double-buffered LDS. Steady state per iteration:
//   issue x-loads(k+1) -> NT-store sub k from LDS -> combine+ds_write(k+1)
//   -> [lgkmcnt(0) + raw s_barrier]          (NO vmcnt drain at barriers!)
// so global loads and NT stores stay in flight across barriers and the write
// stream never stalls on the load queue. LUT is computed once per (ii,dd,b)
// and each thread's two LUT entries live in registers for the whole kernel.
// XCD-band swizzle (R3's confirmed win) retained: 1728 = 8 XCD * 216 slots.

#define NAA 81
#define H 96
#define W 96
#define NC 4
#define ND 9
#define PLANE 9216          // 96*96
#define NR 324              // rows = c*81+uv
#define SUB 16              // j per sub-chunk
#define NSUB 6              // 96 / SUB
#define SUBV (SUB * NR / 4) // 1296 vec4 stores per sub
#define OUTROW 31104        // W*NR
#define CTR_OFF 53747712LL  // 2*9*96*96*324
#define XTOT 5971968        // total floats in x

typedef float f32x4 __attribute__((ext_vector_type(4)));
typedef f32x4 __attribute__((aligned(4))) f32x4u;   // 4B-aligned vector load

// Barrier that drains only LDS ops: global loads/stores stay in flight.
#define BAR() do { \
    asm volatile("s_waitcnt lgkmcnt(0)" ::: "memory"); \
    __builtin_amdgcn_s_barrier(); \
} while (0)

__device__ __forceinline__ f32x4 combine(f32x4 xv, f32x4 mv, int xb, int col0) {
    f32x4 r;
    bool rv = xb >= 0;
    r.x = (rv && (unsigned)(col0 + 0) < (unsigned)W) ? xv.x * mv.x : 0.0f;
    r.y = (rv && (unsigned)(col0 + 1) < (unsigned)W) ? xv.y * mv.y : 0.0f;
    r.z = (rv && (unsigned)(col0 + 2) < (unsigned)W) ? xv.z * mv.z : 0.0f;
    r.w = (rv && (unsigned)(col0 + 3) < (unsigned)W) ? xv.w * mv.w : 0.0f;
    return r;
}

__global__ __launch_bounds__(512, 6)
void build_cost_kernel(const float* __restrict__ x, const float* __restrict__ mask,
                       float* __restrict__ out) {
    __shared__ __align__(16) float xs0[SUB * NR];   // 20,736 B ping
    __shared__ __align__(16) float xs1[SUB * NR];   // 20,736 B pong
    __shared__ __align__(16) int   lut[2 * NR];     //  2,592 B

    // ---- XCD-band swizzle decode (bijective: 1728 = 8 * 216) ----
    const int D   = blockIdx.x;      // 0..1727
    const int xcd = D & 7;           // target XCD (HW round-robin over dispatch id)
    const int s_  = D >> 3;          // 0..215: slot within XCD
    const int b   = s_ / 108;        // slowest: batch
    const int w_  = s_ - 108 * b;    // 0..107
    const int dd  = w_ / 12;         // slow: disparity 0..8
    const int iio = w_ - 12 * dd;    // fast: ii within band
    const int ii  = 12 * xcd + iio;  // spatial row
    const int d   = dd - 4;
    const int tid = threadIdx.x;

    // ---- phase 0: packed per-row LUT (324 rows) ----
    if (tid < NR) {
        int row = tid;                   // row = c*81 + uv
        int c  = row / 81;
        int uv = row - 81 * c;
        int u  = uv / 9;
        int v  = uv - 9 * u;
        int ri = ii + d * (4 - u);
        int xb = ((b * NC + c) * NAA + uv) * PLANE + ri * W;
        int mb = ((b * NAA + uv) * H + ii) * W;
        int s  = d * (4 - v);
        lut[2 * tid]     = ((unsigned)ri < (unsigned)H) ? xb : -1;
        lut[2 * tid + 1] = (mb << 6) | (s + 16);
    }
    BAR();

    // ---- ctr output: x[b,c,40,ii,:] (one block per (ii,b) at dd==4) ----
    if (dd == 4 && tid < 96) {
        int c = tid / 24;
        int q = tid - 24 * c;
        size_t so  = (size_t)((b * NC + c) * NAA + 40) * PLANE + (size_t)ii * W + 4 * q;
        size_t dst = CTR_OFF + (size_t)((b * NC + c) * H + ii) * W + 4 * q;
        f32x4 cv = *(const f32x4*)(x + so);
        __builtin_nontemporal_store(cv, (f32x4*)(out + dst));
    }

    // ---- per-thread stage item: (row-quad rq, j-quad jb), fixed all subs ----
    const bool active = tid < 4 * NAA;   // 324 stage items
    const int rq = tid >> 2;             // row quad 0..80
    const int jb = (tid & 3) * 4;        // j-quad offset within sub: 0,4,8,12
    int4 P0, P1;                         // rows 4rq..4rq+1, 4rq+2..4rq+3
    if (active) {
        P0 = *(const int4*)&lut[8 * rq];
        P1 = *(const int4*)&lut[8 * rq + 4];
    }

    f32x4 xr0, xr1, xr2, xr3;            // in-flight x tiles for next sub

    auto issue = [&](int j0) {           // issue 4 x-loads for sub at column j0
        xr0 = *(const f32x4u*)(x + min(max(P0.x + j0 + jb + ((P0.y & 63) - 16), 0), XTOT - 4));
        xr1 = *(const f32x4u*)(x + min(max(P0.z + j0 + jb + ((P0.w & 63) - 16), 0), XTOT - 4));
        xr2 = *(const f32x4u*)(x + min(max(P1.x + j0 + jb + ((P1.y & 63) - 16), 0), XTOT - 4));
        xr3 = *(const f32x4u*)(x + min(max(P1.z + j0 + jb + ((P1.w & 63) - 16), 0), XTOT - 4));
    };

    auto combine_write = [&](int j0, float* buf) {
        f32x4 m0 = *(const f32x4*)(mask + (P0.y >> 6) + j0 + jb);
        f32x4 m1 = *(const f32x4*)(mask + (P0.w >> 6) + j0 + jb);
        f32x4 m2 = *(const f32x4*)(mask + (P1.y >> 6) + j0 + jb);
        f32x4 m3 = *(const f32x4*)(mask + (P1.w >> 6) + j0 + jb);
        f32x4 v0 = combine(xr0, m0, P0.x, j0 + jb + ((P0.y & 63) - 16));
        f32x4 v1 = combine(xr1, m1, P0.z, j0 + jb + ((P0.w & 63) - 16));
        f32x4 v2 = combine(xr2, m2, P1.x, j0 + jb + ((P1.y & 63) - 16));
        f32x4 v3 = combine(xr3, m3, P1.z, j0 + jb + ((P1.w & 63) - 16));
        float* bp = buf + 4 * rq + jb * NR;
        f32x4 t0 = {v0.x, v1.x, v2.x, v3.x};
        f32x4 t1 = {v0.y, v1.y, v2.y, v3.y};
        f32x4 t2 = {v0.z, v1.z, v2.z, v3.z};
        f32x4 t3 = {v0.w, v1.w, v2.w, v3.w};
        *(f32x4*)(bp + 0 * NR) = t0;
        *(f32x4*)(bp + 1 * NR) = t1;
        *(f32x4*)(bp + 2 * NR) = t2;
        *(f32x4*)(bp + 3 * NR) = t3;
    };

    const size_t obase = (size_t)((b * ND + dd) * H + ii) * OUTROW;

    auto store_sub = [&](int k, const float* sp) {   // LDS addr = 16*idx bytes, linear
        const size_t cb = obase + (size_t)(SUB * k) * NR;
        #pragma unroll
        for (int m = 0; m < 2; ++m) {
            int idx = tid + 512 * m;
            f32x4 v = *(const f32x4*)(sp + 4 * idx);
            __builtin_nontemporal_store(v, (f32x4*)(out + cb + 4 * (size_t)idx));
        }
        if (tid < SUBV - 1024) {                     // 272 remainder
            int idx = tid + 1024;
            f32x4 v = *(const f32x4*)(sp + 4 * idx);
            __builtin_nontemporal_store(v, (f32x4*)(out + cb + 4 * (size_t)idx));
        }
    };

    // ---- prologue: fill ping buffer ----
    if (active) { issue(0); combine_write(0, xs0); }
    BAR();

    // ---- steady state: store k from one buffer while staging k+1 into other ----
    #pragma unroll
    for (int k = 0; k < NSUB; ++k) {
        float* rbuf = (k & 1) ? xs1 : xs0;
        float* wbuf = (k & 1) ? xs0 : xs1;
        if (k < NSUB - 1 && active) issue(SUB * (k + 1));  // loads in flight...
        store_sub(k, rbuf);                                // ...hide under store stream
        if (k < NSUB - 1 && active) combine_write(SUB * (k + 1), wbuf);
        BAR();
    }
}

extern "C" void kernel_launch(void* const* d_in, const int* in_sizes, int n_in,
                              void* d_out, int out_size, void* d_ws, size_t ws_size,
                              hipStream_t stream) {
    const float* x    = (const float*)d_in[0];
    const float* mask = (const float*)d_in[1];
    float* out = (float*)d_out;
    dim3 grid(1728, 1, 1);   // (ii, dd, b) flattened; XCD-band swizzle in-kernel
    build_cost_kernel<<<grid, 512, 0, stream>>>(x, mask, out);
}

// Round 6
// 246.574 us; speedup vs baseline: 1.0616x; 1.0616x over previous
//
#include <hip/hip_runtime.h>

// cost[b,dd,ii,j,c,uv] = (bounds? x[b,c,uv, ii+d*(4-u), j+d*(4-v)] : 0) * mask[b,uv,ii,j]
// d = dd-4, u=uv/9, v=uv%9.  out = cost (b,9,96,96,324) flat, then ctr = x[:,:,40,:,:].
//
// v6 = R3 (XCD-band swizzle, best so far) with ONE change: all output stores
// are plain (L2 write-allocate) instead of __builtin_nontemporal_store.
// A/B to test whether the nt write path (L2 bypass, 16B-granule streams from
// 24 interleaved waves/CU) is what holds effective write BW at ~2 TB/s.
// The harness fill sustains 6.57 TB/s with plain stores -> plain-store
// streaming provably reaches full BW on this chip.

#define NAA 81
#define H 96
#define W 96
#define NC 4
#define ND 9
#define PLANE 9216          // 96*96
#define NR 324              // rows = c*81+uv
#define JB 32               // j per block
#define OUTROW 31104        // W*NR
#define CTR_OFF 53747712LL  // 2*9*96*96*324
#define XTOT 5971968        // total floats in x

typedef float f32x4 __attribute__((ext_vector_type(4)));
typedef f32x4 __attribute__((aligned(4))) f32x4u;   // 4B-aligned vector load

__global__ __launch_bounds__(512, 6)
void build_cost_kernel(const float* __restrict__ x, const float* __restrict__ mask,
                       float* __restrict__ out) {
    __shared__ __align__(16) float xs[JB * NR];   // xs[jj*NR + row]  (41,472 B)
    __shared__ __align__(16) int   lut[2 * NR];   // per row: {xb_or_-1, (mb<<6)|(s+16)}

    // ---- XCD-band swizzle decode ----
    const int D   = blockIdx.x;      // 0..5183
    const int xcd = D & 7;           // target XCD (HW round-robin over dispatch id)
    const int s_  = D >> 3;          // 0..647: slot within XCD
    const int b   = s_ / 324;        // phase 0..1 = batch
    const int w_  = s_ - 324 * b;    // 0..323
    const int dd  = w_ / 36;         // slow: disparity 0..8
    const int r_  = w_ - 36 * dd;
    const int jc  = r_ / 12;         // mid: j-chunk 0..2
    const int iio = r_ - 12 * jc;    // fast: ii within band
    const int ii  = 12 * xcd + iio;  // spatial row
    const int j0  = JB * jc;
    const int d   = dd - 4;
    const int tid = threadIdx.x;

    // ---- phase 0: packed per-row LUT (324 rows) ----
    if (tid < NR) {
        int row = tid;                   // row = c*81 + uv
        int c  = row / 81;
        int uv = row - 81 * c;
        int u  = uv / 9;
        int v  = uv - 9 * u;
        int ri = ii + d * (4 - u);
        int xb = ((b * NC + c) * NAA + uv) * PLANE + ri * W;
        int mb = ((b * NAA + uv) * H + ii) * W;
        int s  = d * (4 - v);
        lut[2 * tid]     = ((unsigned)ri < (unsigned)H) ? xb : -1;
        lut[2 * tid + 1] = (mb << 6) | (s + 16);
    }
    __syncthreads();

    // ---- phase 1: stage 4x4 tiles. item = (row-quad rq, j-quad j4) ----
    for (int idx = tid; idx < NAA * 8; idx += 512) {
        int rq = idx >> 3;               // row quad 0..80
        int j4 = idx & 7;                // j quad 0..7
        int jb = 4 * j4;
        int4 P0 = *(const int4*)&lut[8 * rq];       // rows 4rq, 4rq+1
        int4 P1 = *(const int4*)&lut[8 * rq + 4];   // rows 4rq+2, 4rq+3

        auto ld = [&](int xb, int B) -> f32x4 {
            int s    = (B & 63) - 16;
            int col0 = j0 + jb + s;
            int a0   = xb + col0;
            int addr = min(max(a0, 0), XTOT - 4);
            f32x4 xv = *(const f32x4u*)(x + addr);
            f32x4 mv = *(const f32x4*)(mask + (B >> 6) + j0 + jb);
            f32x4 r;
            bool rv = (xb >= 0);
            r.x = (rv && (unsigned)(col0 + 0) < (unsigned)W) ? xv.x * mv.x : 0.0f;
            r.y = (rv && (unsigned)(col0 + 1) < (unsigned)W) ? xv.y * mv.y : 0.0f;
            r.z = (rv && (unsigned)(col0 + 2) < (unsigned)W) ? xv.z * mv.z : 0.0f;
            r.w = (rv && (unsigned)(col0 + 3) < (unsigned)W) ? xv.w * mv.w : 0.0f;
            return r;
        };

        f32x4 v0 = ld(P0.x, P0.y);
        f32x4 v1 = ld(P0.z, P0.w);
        f32x4 v2 = ld(P1.x, P1.y);
        f32x4 v3 = ld(P1.z, P1.w);

        // transpose 4x4 in registers; column t -> rows 4rq..4rq+3 at jj=jb+t
        float* base = &xs[4 * rq];
        f32x4 w0 = {v0.x, v1.x, v2.x, v3.x};
        f32x4 w1 = {v0.y, v1.y, v2.y, v3.y};
        f32x4 w2 = {v0.z, v1.z, v2.z, v3.z};
        f32x4 w3 = {v0.w, v1.w, v2.w, v3.w};
        *(f32x4*)(base + (jb + 0) * NR) = w0;
        *(f32x4*)(base + (jb + 1) * NR) = w1;
        *(f32x4*)(base + (jb + 2) * NR) = w2;
        *(f32x4*)(base + (jb + 3) * NR) = w3;
    }
    __syncthreads();

    // ---- phase 2: contiguous, aligned stores in output order (PLAIN stores) ----
    // out offset = obase + 4*idx; LDS addr = 16*idx bytes (purely linear,
    // conflict-free b128 reads).
    const size_t obase = (size_t)((b * ND + dd) * H + ii) * OUTROW + (size_t)j0 * NR;
    for (int idx = tid; idx < NAA * JB; idx += 512) {
        f32x4 v = *(const f32x4*)&xs[4 * idx];
        *(f32x4*)(out + obase + 4 * (size_t)idx) = v;
    }

    // ---- ctr output: x[b,c,40,ii,:] (done by dd==4, jc==0 blocks) ----
    if (dd == 4 && jc == 0 && tid < 96) {
        int c = tid / 24;
        int q = tid - 24 * c;
        size_t so  = (size_t)((b * NC + c) * NAA + 40) * PLANE + (size_t)ii * W + 4 * q;
        size_t dst = CTR_OFF + (size_t)((b * NC + c) * H + ii) * W + 4 * q;
        f32x4 cv = *(const f32x4*)(x + so);
        *(f32x4*)(out + dst) = cv;
    }
}

extern "C" void kernel_launch(void* const* d_in, const int* in_sizes, int n_in,
                              void* d_out, int out_size, void* d_ws, size_t ws_size,
                              hipStream_t stream) {
    const float* x    = (const float*)d_in[0];
    const float* mask = (const float*)d_in[1];
    float* out = (float*)d_out;
    dim3 grid(5184, 1, 1);   // flattened; XCD-band swizzle decoded in-kernel
    build_cost_kernel<<<grid, 512, 0, stream>>>(x, mask, out);
}